// Round 3
// baseline (543.705 us; speedup 1.0000x reference)
//
#include <hip/hip_runtime.h>
#include <hip/hip_bf16.h>

// Problem constants
#define Bb 2
#define Ss 2048
#define Ee 2048
#define Hh 16
#define Dd 128
#define Mrows (Bb*Ss)   // 4096

typedef short short8 __attribute__((ext_vector_type(8)));
typedef float f32x4 __attribute__((ext_vector_type(4)));

__device__ __forceinline__ unsigned short bf_rne(float f) {
    unsigned u = __builtin_bit_cast(unsigned, f);
    u += 0x7fffu + ((u >> 16) & 1u);
    return (unsigned short)(u >> 16);
}
__device__ __forceinline__ float bf2f(unsigned short x) {
    unsigned u = ((unsigned)x) << 16;
    return __builtin_bit_cast(float, u);
}
__device__ __forceinline__ void load_lds16(const void* g, void* l) {
    __builtin_amdgcn_global_load_lds(
        (const __attribute__((address_space(1))) unsigned int*)g,
        (__attribute__((address_space(3))) unsigned int*)l, 16, 0, 0);
}

// ---------------- fp32 -> bf16 cast ----------------
__global__ void cast4_kernel(const float4* __restrict__ in, ushort4* __restrict__ out, int n4) {
    int i = blockIdx.x * 256 + threadIdx.x;
    if (i < n4) {
        float4 v = in[i];
        ushort4 o;
        o.x = bf_rne(v.x); o.y = bf_rne(v.y); o.z = bf_rne(v.z); o.w = bf_rne(v.w);
        out[i] = o;
    }
}

// ---------------- GEMM: C[m,n] = sum_k A[m,k]*W[n,k] + bias ----------------
// mode 0: fp32 C[m*N+n], bias[n].
// mode 1: bf16 [B,H,S,D] (m=token, n=feature), bias[n].
// mode 2: bf16 [B,H,D,S] (m=feature, n=token), bias[m]   (V^T output).
__global__ __launch_bounds__(256) void gemm_bt(
    const short* __restrict__ A, const short* __restrict__ W,
    const float* __restrict__ bias, float* __restrict__ Cf, short* __restrict__ Cb,
    int M, int N, int K, int mode)
{
    __shared__ short As[128*32];
    __shared__ short Bs[128*32];
    const int tid  = threadIdx.x;
    const int wave = tid >> 6;
    const int lane = tid & 63;
    const int quad = lane >> 4;
    const int l16  = lane & 15;
    const int m0 = blockIdx.x * 128;
    const int n0 = blockIdx.y * 128;
    const int wm = (wave & 1) * 64;
    const int wn = (wave >> 1) * 64;

    f32x4 acc[4][4] = {};

    const int srow = wave * 32 + (lane >> 2);
    const int scol = (lane & 3) * 8;
    const size_t a_base = (size_t)(m0 + srow) * K + scol;
    const size_t b_base = (size_t)(n0 + srow) * K + scol;

    for (int kt = 0; kt < K; kt += 32) {
        __syncthreads();
        load_lds16(A + a_base + kt,                 &As[(wave*32) * 32]);
        load_lds16(A + a_base + (size_t)16*K + kt,  &As[(wave*32 + 16) * 32]);
        load_lds16(W + b_base + kt,                 &Bs[(wave*32) * 32]);
        load_lds16(W + b_base + (size_t)16*K + kt,  &Bs[(wave*32 + 16) * 32]);
        __syncthreads();

        short8 af[4], bfr[4];
        #pragma unroll
        for (int i = 0; i < 4; ++i)
            af[i] = *(const short8*)&As[(wm + i*16 + l16)*32 + quad*8];
        #pragma unroll
        for (int j = 0; j < 4; ++j)
            bfr[j] = *(const short8*)&Bs[(wn + j*16 + l16)*32 + quad*8];
        #pragma unroll
        for (int i = 0; i < 4; ++i)
            #pragma unroll
            for (int j = 0; j < 4; ++j)
                acc[i][j] = __builtin_amdgcn_mfma_f32_16x16x32_bf16(af[i], bfr[j], acc[i][j], 0, 0, 0);
    }

    #pragma unroll
    for (int i = 0; i < 4; ++i) {
        #pragma unroll
        for (int j = 0; j < 4; ++j) {
            #pragma unroll
            for (int r = 0; r < 4; ++r) {
                int gm = m0 + wm + i*16 + quad*4 + r;
                int gn = n0 + wn + j*16 + l16;
                if (mode == 0) {
                    Cf[(size_t)gm * N + gn] = acc[i][j][r] + bias[gn];
                } else if (mode == 1) {
                    float v = acc[i][j][r] + bias[gn];
                    int b = gm >> 11, s = gm & (Ss-1);
                    int h = gn >> 7,  d = gn & (Dd-1);
                    Cb[(((size_t)(b*Hh + h)) * Ss + s) * Dd + d] = (short)bf_rne(v);
                } else {
                    float v = acc[i][j][r] + bias[gm];
                    int h = gm >> 7,  d = gm & (Dd-1);
                    int b = gn >> 11, s = gn & (Ss-1);
                    Cb[(((size_t)(b*Hh + h)) * Dd + d) * Ss + s] = (short)bf_rne(v);
                }
            }
        }
    }
}

// ---------------- RoPE in place on [B,H,S,D] bf16 ----------------
__global__ void rope_kernel(short* __restrict__ X, const float* __restrict__ cosT,
                            const float* __restrict__ sinT, float scale) {
    int idx = blockIdx.x * 256 + threadIdx.x;
    int d  = idx & 63;
    int s  = (idx >> 6) & (Ss - 1);
    int bh = idx >> 17;
    size_t base = ((size_t)bh * Ss + s) * Dd;
    float x1 = bf2f((unsigned short)X[base + d]);
    float x2 = bf2f((unsigned short)X[base + d + 64]);
    float c  = cosT[s*Dd + d];
    float sn = sinT[s*Dd + d];
    float y1 = (x1 * c - x2 * sn) * scale;
    float y2 = (x2 * c + x1 * sn) * scale;
    X[base + d]      = (short)bf_rne(y1);
    X[base + d + 64] = (short)bf_rne(y2);
}

// ---------------- Flash attention (causal), bf16 MFMA ----------------
// Q,K: [B,H,S,D] bf16 (Q pre-scaled by 1/sqrt(D)); VT: [B,H,D,S] bf16. O: [B,S,E] bf16.
// Block: 256 thr (4 waves); Q-tile 128 rows (wave = 32 rows = 2 m-frags); K-tile 64.
// K/V staged via global_load_lds with XOR chunk-swizzle (conflict-free unpadded reads).
__global__ __launch_bounds__(256, 2) void attn_kernel(
    const short* __restrict__ Q, const short* __restrict__ Kk,
    const short* __restrict__ VT, short* __restrict__ O)
{
    __shared__ short Ks[64*128];        // 16 KB, chunk c stored at c^(row&15)
    __shared__ short Vt[2][128*64];     // 2 x 16 KB, chunk c stored at c^(row&7)
    __shared__ short Pw[4][32*72];      // per-wave P, padded stride 72

    const int tid  = threadIdx.x;
    const int wave = tid >> 6;
    const int lane = tid & 63;
    const int quad = lane >> 4;
    const int l16  = lane & 15;
    const int mmap = (blockIdx.x + blockIdx.y) & 15;
    const int qt   = (blockIdx.y & 16) ? (15 - mmap) : mmap;   // balanced: blocks c & c+256 sum to 17 units
    const int bh = blockIdx.y;
    const int b  = bh >> 4, h = bh & 15;
    const size_t head_off = (size_t)bh * Ss * Dd;
    const short* Kg  = Kk + head_off;
    const short* VTg = VT + head_off;   // [D][S] for this head

    auto stageK = [&](int kt) {
        #pragma unroll
        for (int j = 0; j < 4; ++j) {
            int r = wave*16 + j*4 + (lane >> 4);
            int c = (lane & 15) ^ (r & 15);
            load_lds16(Kg + (size_t)(kt*64 + r)*Dd + c*8, &Ks[(wave*16 + j*4)*128]);
        }
    };
    auto stageV = [&](int kt, int buf) {
        #pragma unroll
        for (int j = 0; j < 4; ++j) {
            int r = wave*32 + j*8 + (lane >> 3);
            int c = (lane & 7) ^ (r & 7);
            load_lds16(VTg + (size_t)r*Ss + kt*64 + c*8, &Vt[buf][(wave*32 + j*8)*64]);
        }
    };

    // Q fragments: 2 m-frags x 4 k-steps
    const int qbase = qt*128 + wave*32;
    short8 qf[2][4];
    #pragma unroll
    for (int mi = 0; mi < 2; ++mi)
        #pragma unroll
        for (int ds = 0; ds < 4; ++ds)
            qf[mi][ds] = *(const short8*)&Q[head_off + (size_t)(qbase + mi*16 + l16)*Dd + ds*32 + quad*8];

    f32x4 o[2][8] = {};
    float m_i[2][4], l_i[2][4];
    #pragma unroll
    for (int mi = 0; mi < 2; ++mi)
        #pragma unroll
        for (int r = 0; r < 4; ++r) { m_i[mi][r] = -__builtin_inff(); l_i[mi][r] = 0.f; }

    const int ktiles = 2*qt + 2;
    stageK(0);
    stageV(0, 0);

    for (int kt = 0; kt < ktiles; ++kt) {
        __syncthreads();                 // drains DMA: Ks=kt, Vt[kt&1]=kt ready
        if (kt + 1 < ktiles) stageV(kt+1, (kt+1)&1);

        // S = Q K^T
        f32x4 sc[2][4] = {};
        #pragma unroll
        for (int jk = 0; jk < 4; ++jk)
            #pragma unroll
            for (int ds = 0; ds < 4; ++ds) {
                short8 kf = *(const short8*)&Ks[(jk*16 + l16)*128 + (((ds*4 + quad) ^ l16) * 8)];
                #pragma unroll
                for (int mi = 0; mi < 2; ++mi)
                    sc[mi][jk] = __builtin_amdgcn_mfma_f32_16x16x32_bf16(qf[mi][ds], kf, sc[mi][jk], 0, 0, 0);
            }

        __syncthreads();                 // all waves done reading Ks
        if (kt + 1 < ktiles) stageK(kt+1);

        const int k0 = kt*64;
        // causal mask (only frags the diagonal touches)
        #pragma unroll
        for (int mi = 0; mi < 2; ++mi) {
            if (k0 + 63 > qbase + mi*16) {
                #pragma unroll
                for (int jk = 0; jk < 4; ++jk) {
                    int kg = k0 + jk*16 + l16;
                    #pragma unroll
                    for (int r = 0; r < 4; ++r)
                        if (kg > qbase + mi*16 + quad*4 + r) sc[mi][jk][r] = -__builtin_inff();
                }
            }
        }

        // online softmax (row stats across 16 lanes; sum kept per-lane partial)
        float alpha[2][4];
        #pragma unroll
        for (int mi = 0; mi < 2; ++mi)
            #pragma unroll
            for (int r = 0; r < 4; ++r) {
                float mx = fmaxf(fmaxf(sc[mi][0][r], sc[mi][1][r]), fmaxf(sc[mi][2][r], sc[mi][3][r]));
                #pragma unroll
                for (int off = 1; off < 16; off <<= 1)
                    mx = fmaxf(mx, __shfl_xor(mx, off));
                float mn = fmaxf(m_i[mi][r], mx);
                alpha[mi][r] = __expf(m_i[mi][r] - mn);
                m_i[mi][r] = mn;
                float s = 0.f;
                #pragma unroll
                for (int jk = 0; jk < 4; ++jk) {
                    float p = __expf(sc[mi][jk][r] - mn);
                    sc[mi][jk][r] = p;
                    s += p;
                }
                l_i[mi][r] = l_i[mi][r] * alpha[mi][r] + s;
            }

        // P (C/D layout) -> per-wave LDS -> A-operand layout
        #pragma unroll
        for (int mi = 0; mi < 2; ++mi)
            #pragma unroll
            for (int jk = 0; jk < 4; ++jk)
                #pragma unroll
                for (int r = 0; r < 4; ++r)
                    Pw[wave][(mi*16 + quad*4 + r)*72 + jk*16 + l16] = (short)bf_rne(sc[mi][jk][r]);

        #pragma unroll
        for (int mi = 0; mi < 2; ++mi)
            #pragma unroll
            for (int dt = 0; dt < 8; ++dt)
                #pragma unroll
                for (int r = 0; r < 4; ++r)
                    o[mi][dt][r] *= alpha[mi][r];

        short8 pa[2][2];
        #pragma unroll
        for (int mi = 0; mi < 2; ++mi)
            #pragma unroll
            for (int kk = 0; kk < 2; ++kk)
                pa[mi][kk] = *(const short8*)&Pw[wave][(mi*16 + l16)*72 + kk*32 + quad*8];

        const short* vb = Vt[kt & 1];
        #pragma unroll
        for (int dt = 0; dt < 8; ++dt)
            #pragma unroll
            for (int kk = 0; kk < 2; ++kk) {
                short8 vf = *(const short8*)&vb[(dt*16 + l16)*64 + (((kk*4 + quad) ^ (l16 & 7)) * 8)];
                #pragma unroll
                for (int mi = 0; mi < 2; ++mi)
                    o[mi][dt] = __builtin_amdgcn_mfma_f32_16x16x32_bf16(pa[mi][kk], vf, o[mi][dt], 0, 0, 0);
            }
    }

    // epilogue
    #pragma unroll
    for (int mi = 0; mi < 2; ++mi)
        #pragma unroll
        for (int r = 0; r < 4; ++r) {
            float l = l_i[mi][r];
            #pragma unroll
            for (int off = 1; off < 16; off <<= 1)
                l += __shfl_xor(l, off);
            float inv = 1.0f / l;
            int srow = qbase + mi*16 + quad*4 + r;
            size_t obase = ((size_t)b * Ss + srow) * Ee + h * Dd;
            #pragma unroll
            for (int dt = 0; dt < 8; ++dt)
                O[obase + dt*16 + l16] = (short)bf_rne(o[mi][dt][r] * inv);
        }
}

extern "C" void kernel_launch(void* const* d_in, const int* in_sizes, int n_in,
                              void* d_out, int out_size, void* d_ws, size_t ws_size,
                              hipStream_t stream) {
    const float* x_q  = (const float*)d_in[0];
    const float* x_kv = (const float*)d_in[1];
    const float* cosT = (const float*)d_in[2];
    const float* sinT = (const float*)d_in[3];
    const float* wq = (const float*)d_in[4];
    const float* bq = (const float*)d_in[5];
    const float* wk = (const float*)d_in[6];
    const float* bk = (const float*)d_in[7];
    const float* wv = (const float*)d_in[8];
    const float* bv = (const float*)d_in[9];
    const float* wo = (const float*)d_in[10];
    const float* bo = (const float*)d_in[11];

    size_t off = 0;
    auto alloc = [&](size_t bytes) {
        void* p = (char*)d_ws + off;
        off += (bytes + 255) & ~(size_t)255;
        return p;
    };
    const size_t nX = (size_t)Mrows * Ee;
    const size_t nW = (size_t)Ee * Ee;
    short* xq16  = (short*)alloc(nX * 2);
    short* xkv16 = (short*)alloc(nX * 2);
    short* wq16  = (short*)alloc(nW * 2);
    short* wk16  = (short*)alloc(nW * 2);
    short* wv16  = (short*)alloc(nW * 2);
    short* wo16  = (short*)alloc(nW * 2);
    short* Qr    = (short*)alloc(nX * 2);      // [B,H,S,D]
    short* Kr    = (short*)alloc(nX * 2);      // [B,H,S,D]
    short* VTb   = (short*)alloc(nX * 2);      // [B,H,D,S]
    short* Ob    = (short*)alloc(nX * 2);      // [B,S,E]

    cast4_kernel<<<(int)(nX/4 + 255)/256, 256, 0, stream>>>((const float4*)x_q,  (ushort4*)xq16,  (int)(nX/4));
    cast4_kernel<<<(int)(nX/4 + 255)/256, 256, 0, stream>>>((const float4*)x_kv, (ushort4*)xkv16, (int)(nX/4));
    cast4_kernel<<<(int)(nW/4 + 255)/256, 256, 0, stream>>>((const float4*)wq, (ushort4*)wq16, (int)(nW/4));
    cast4_kernel<<<(int)(nW/4 + 255)/256, 256, 0, stream>>>((const float4*)wk, (ushort4*)wk16, (int)(nW/4));
    cast4_kernel<<<(int)(nW/4 + 255)/256, 256, 0, stream>>>((const float4*)wv, (ushort4*)wv16, (int)(nW/4));
    cast4_kernel<<<(int)(nW/4 + 255)/256, 256, 0, stream>>>((const float4*)wo, (ushort4*)wo16, (int)(nW/4));

    dim3 ggrid(Mrows/128, Ee/128);
    gemm_bt<<<ggrid, 256, 0, stream>>>(xq16,  wq16, bq, nullptr, Qr, Mrows, Ee, Ee, 1);
    gemm_bt<<<ggrid, 256, 0, stream>>>(xkv16, wk16, bk, nullptr, Kr, Mrows, Ee, Ee, 1);
    // V^T = (x_kv @ wv^T)^T via swapped operands -> [B,H,D,S], coalesced stores
    gemm_bt<<<dim3(Ee/128, Mrows/128), 256, 0, stream>>>(wv16, xkv16, bv, nullptr, VTb, Ee, Mrows, Ee, 2);

    int rope_blocks = (Bb*Hh*Ss*64) / 256;
    rope_kernel<<<rope_blocks, 256, 0, stream>>>(Qr, cosT, sinT, 0.08838834764831845f);
    rope_kernel<<<rope_blocks, 256, 0, stream>>>(Kr, cosT, sinT, 1.0f);

    attn_kernel<<<dim3(16, Bb*Hh), 256, 0, stream>>>(Qr, Kr, VTb, Ob);

    gemm_bt<<<ggrid, 256, 0, stream>>>(Ob, wo16, bo, (float*)d_out, nullptr, Mrows, Ee, Ee, 0);
}

// Round 4
// 458.388 us; speedup vs baseline: 1.1861x; 1.1861x over previous
//
#include <hip/hip_runtime.h>
#include <hip/hip_bf16.h>

// Problem constants
#define Bb 2
#define Ss 2048
#define Ee 2048
#define Hh 16
#define Dd 128
#define Mrows (Bb*Ss)   // 4096

typedef short short8 __attribute__((ext_vector_type(8)));
typedef float f32x4 __attribute__((ext_vector_type(4)));

__device__ __forceinline__ unsigned short bf_rne(float f) {
    unsigned u = __builtin_bit_cast(unsigned, f);
    u += 0x7fffu + ((u >> 16) & 1u);
    return (unsigned short)(u >> 16);
}
__device__ __forceinline__ float bf2f(unsigned short x) {
    unsigned u = ((unsigned)x) << 16;
    return __builtin_bit_cast(float, u);
}
__device__ __forceinline__ void load_lds16(const void* g, void* l) {
    __builtin_amdgcn_global_load_lds(
        (const __attribute__((address_space(1))) unsigned int*)g,
        (__attribute__((address_space(3))) unsigned int*)l, 16, 0, 0);
}

// ---------------- fused fp32 -> bf16 cast of all 6 tensors ----------------
// Segments (float4 units): xq 2097152 | xkv 2097152 | wq,wk,wv,wo 1048576 each.
// Outputs are contiguous in ws starting at out base.
__global__ void cast_all_kernel(const float4* __restrict__ xq, const float4* __restrict__ xkv,
                                const float4* __restrict__ wq, const float4* __restrict__ wk,
                                const float4* __restrict__ wv, const float4* __restrict__ wo,
                                ushort4* __restrict__ out) {
    int i = blockIdx.x * 256 + threadIdx.x;
    const float4* src;
    int rel;
    if (i < 2097152)       { src = xq;  rel = i; }
    else if (i < 4194304)  { src = xkv; rel = i - 2097152; }
    else if (i < 5242880)  { src = wq;  rel = i - 4194304; }
    else if (i < 6291456)  { src = wk;  rel = i - 5242880; }
    else if (i < 7340032)  { src = wv;  rel = i - 6291456; }
    else                   { src = wo;  rel = i - 7340032; }
    float4 v = src[rel];
    ushort4 o;
    o.x = bf_rne(v.x); o.y = bf_rne(v.y); o.z = bf_rne(v.z); o.w = bf_rne(v.w);
    out[i] = o;
}

// ---------------- shared GEMM core: 128x128 tile, BK=64, XOR-swizzled LDS ----------------
// A: [M][K] bf16 row-major; W: [N][K] bf16 row-major. acc[i][j] += A tile * W tile^T.
// LDS layout: row-major [row][64], chunk c (8 shorts) of row r stored at slot c^(r&7).
__device__ __forceinline__ void gemm_core(
    const short* __restrict__ A, const short* __restrict__ W, int K,
    int m0, int n0, int wave, int lane, short* As, short* Bs, f32x4 acc[4][4])
{
    const int wm = (wave & 1) * 64;
    const int wn = (wave >> 1) * 64;
    const int quad = lane >> 4;
    const int l16  = lane & 15;
    const int lrow   = lane >> 3;           // 0..7
    const int gchunk = (lane & 7) ^ lrow;   // global chunk this lane fetches

    for (int kt = 0; kt < K; kt += 64) {
        __syncthreads();
        #pragma unroll
        for (int j = 0; j < 4; ++j) {
            int row = wave*32 + j*8 + lrow;
            load_lds16(A + (size_t)(m0 + row)*K + kt + gchunk*8, &As[(wave*32 + j*8)*64]);
            load_lds16(W + (size_t)(n0 + row)*K + kt + gchunk*8, &Bs[(wave*32 + j*8)*64]);
        }
        __syncthreads();

        #pragma unroll
        for (int ks = 0; ks < 64; ks += 32) {
            const int cs = ks >> 3;   // 0 or 4
            short8 af[4], bfr[4];
            #pragma unroll
            for (int i = 0; i < 4; ++i)
                af[i] = *(const short8*)&As[(wm + i*16 + l16)*64 + (((cs + quad) ^ (l16 & 7)) << 3)];
            #pragma unroll
            for (int j = 0; j < 4; ++j)
                bfr[j] = *(const short8*)&Bs[(wn + j*16 + l16)*64 + (((cs + quad) ^ (l16 & 7)) << 3)];
            #pragma unroll
            for (int i = 0; i < 4; ++i)
                #pragma unroll
                for (int j = 0; j < 4; ++j)
                    acc[i][j] = __builtin_amdgcn_mfma_f32_16x16x32_bf16(af[i], bfr[j], acc[i][j], 0, 0, 0);
        }
    }
}

union GemmSmem {
    struct { short As[128*64]; short Bs[128*64]; } st;   // 32 KB staging
    short T[128*137];                                     // 35 KB transpose buffer
};

// ---------------- fused QKV projection ----------------
// grid (32, 48): by>>4 selects sub-problem (0=Q,1=K,2=V), by&15 = n-block (head).
// Q,K -> [B,H,S,D] bf16. V -> [B,H,D,S] bf16 via LDS transpose epilogue.
__global__ __launch_bounds__(256) void qkv_gemm(
    const short* __restrict__ xq, const short* __restrict__ xkv,
    const short* __restrict__ wq, const short* __restrict__ wk, const short* __restrict__ wv,
    const float* __restrict__ bq, const float* __restrict__ bk, const float* __restrict__ bv,
    short* __restrict__ Qr, short* __restrict__ Kr, short* __restrict__ VT)
{
    __shared__ GemmSmem sm;
    const int tid  = threadIdx.x;
    const int wave = tid >> 6;
    const int lane = tid & 63;
    const int quad = lane >> 4;
    const int l16  = lane & 15;
    const int m0   = blockIdx.x * 128;
    const int sub  = blockIdx.y >> 4;
    const int nb   = blockIdx.y & 15;
    const int n0   = nb * 128;
    const int wm = (wave & 1) * 64;
    const int wn = (wave >> 1) * 64;

    const short* A = (sub == 0) ? xq : xkv;
    const short* W = (sub == 0) ? wq : (sub == 1) ? wk : wv;
    const float* bias = (sub == 0) ? bq : (sub == 1) ? bk : bv;

    f32x4 acc[4][4] = {};
    gemm_core(A, W, Ee, m0, n0, wave, lane, sm.st.As, sm.st.Bs, acc);

    const int b0 = m0 >> 11;          // batch (tile never crosses batch)
    const int s0 = m0 & (Ss - 1);

    if (sub < 2) {
        short* out = (sub == 0) ? Qr : Kr;
        #pragma unroll
        for (int i = 0; i < 4; ++i)
            #pragma unroll
            for (int j = 0; j < 4; ++j)
                #pragma unroll
                for (int r = 0; r < 4; ++r) {
                    int gm = m0 + wm + i*16 + quad*4 + r;
                    int gn = n0 + wn + j*16 + l16;
                    float v = acc[i][j][r] + bias[gn];
                    int b = gm >> 11, s = gm & (Ss-1);
                    int h = gn >> 7,  d = gn & (Dd-1);
                    out[(((size_t)(b*Hh + h)) * Ss + s) * Dd + d] = (short)bf_rne(v);
                }
    } else {
        // V: write acc into LDS [s_local][d] (stride 137), then store transposed.
        __syncthreads();   // all waves done with staging LDS (union overwrite)
        #pragma unroll
        for (int i = 0; i < 4; ++i)
            #pragma unroll
            for (int j = 0; j < 4; ++j)
                #pragma unroll
                for (int r = 0; r < 4; ++r) {
                    int ml = wm + i*16 + quad*4 + r;      // s-local
                    int nl = wn + j*16 + l16;             // d
                    sm.T[ml*137 + nl] = (short)bf_rne(acc[i][j][r] + bias[n0 + nl]);
                }
        __syncthreads();
        const int g = tid & 15, dbase = tid >> 4;
        const int h = nb;
        #pragma unroll
        for (int dd = 0; dd < 8; ++dd) {
            int d = dbase + dd*16;
            short8 v;
            #pragma unroll
            for (int c = 0; c < 8; ++c)
                v[c] = sm.T[(g*8 + c)*137 + d];
            *(short8*)&VT[(((size_t)(b0*Hh + h)) * Dd + d) * Ss + s0 + g*8] = v;
        }
    }
}

// ---------------- O-projection: fp32 out = Ob @ wo^T + bo ----------------
__global__ __launch_bounds__(256) void oproj_gemm(
    const short* __restrict__ A, const short* __restrict__ W,
    const float* __restrict__ bias, float* __restrict__ Cf)
{
    __shared__ GemmSmem sm;
    const int tid  = threadIdx.x;
    const int wave = tid >> 6;
    const int lane = tid & 63;
    const int quad = lane >> 4;
    const int l16  = lane & 15;
    const int m0 = blockIdx.x * 128;
    const int n0 = blockIdx.y * 128;
    const int wm = (wave & 1) * 64;
    const int wn = (wave >> 1) * 64;

    f32x4 acc[4][4] = {};
    gemm_core(A, W, Ee, m0, n0, wave, lane, sm.st.As, sm.st.Bs, acc);

    #pragma unroll
    for (int i = 0; i < 4; ++i)
        #pragma unroll
        for (int j = 0; j < 4; ++j)
            #pragma unroll
            for (int r = 0; r < 4; ++r) {
                int gm = m0 + wm + i*16 + quad*4 + r;
                int gn = n0 + wn + j*16 + l16;
                Cf[(size_t)gm * Ee + gn] = acc[i][j][r] + bias[gn];
            }
}

// ---------------- RoPE in place on [B,H,S,D] bf16 (Q and K in one dispatch) ----------------
__global__ void rope_kernel(short* __restrict__ Qr, short* __restrict__ Kr,
                            const float* __restrict__ cosT, const float* __restrict__ sinT) {
    short* X    = blockIdx.y ? Kr : Qr;
    float scale = blockIdx.y ? 1.0f : 0.08838834764831845f;
    int idx = blockIdx.x * 256 + threadIdx.x;
    int d  = idx & 63;
    int s  = (idx >> 6) & (Ss - 1);
    int bh = idx >> 17;
    size_t base = ((size_t)bh * Ss + s) * Dd;
    float x1 = bf2f((unsigned short)X[base + d]);
    float x2 = bf2f((unsigned short)X[base + d + 64]);
    float c  = cosT[s*Dd + d];
    float sn = sinT[s*Dd + d];
    X[base + d]      = (short)bf_rne((x1 * c - x2 * sn) * scale);
    X[base + d + 64] = (short)bf_rne((x2 * c + x1 * sn) * scale);
}

// ---------------- Flash attention (causal), bf16 MFMA (unchanged from R3) ----------------
__global__ __launch_bounds__(256, 2) void attn_kernel(
    const short* __restrict__ Q, const short* __restrict__ Kk,
    const short* __restrict__ VT, short* __restrict__ O)
{
    __shared__ short Ks[64*128];
    __shared__ short Vt[2][128*64];
    __shared__ short Pw[4][32*72];

    const int tid  = threadIdx.x;
    const int wave = tid >> 6;
    const int lane = tid & 63;
    const int quad = lane >> 4;
    const int l16  = lane & 15;
    const int mmap = (blockIdx.x + blockIdx.y) & 15;
    const int qt   = (blockIdx.y & 16) ? (15 - mmap) : mmap;
    const int bh = blockIdx.y;
    const int b  = bh >> 4, h = bh & 15;
    const size_t head_off = (size_t)bh * Ss * Dd;
    const short* Kg  = Kk + head_off;
    const short* VTg = VT + head_off;

    auto stageK = [&](int kt) {
        #pragma unroll
        for (int j = 0; j < 4; ++j) {
            int r = wave*16 + j*4 + (lane >> 4);
            int c = (lane & 15) ^ (r & 15);
            load_lds16(Kg + (size_t)(kt*64 + r)*Dd + c*8, &Ks[(wave*16 + j*4)*128]);
        }
    };
    auto stageV = [&](int kt, int buf) {
        #pragma unroll
        for (int j = 0; j < 4; ++j) {
            int r = wave*32 + j*8 + (lane >> 3);
            int c = (lane & 7) ^ (r & 7);
            load_lds16(VTg + (size_t)r*Ss + kt*64 + c*8, &Vt[buf][(wave*32 + j*8)*64]);
        }
    };

    const int qbase = qt*128 + wave*32;
    short8 qf[2][4];
    #pragma unroll
    for (int mi = 0; mi < 2; ++mi)
        #pragma unroll
        for (int ds = 0; ds < 4; ++ds)
            qf[mi][ds] = *(const short8*)&Q[head_off + (size_t)(qbase + mi*16 + l16)*Dd + ds*32 + quad*8];

    f32x4 o[2][8] = {};
    float m_i[2][4], l_i[2][4];
    #pragma unroll
    for (int mi = 0; mi < 2; ++mi)
        #pragma unroll
        for (int r = 0; r < 4; ++r) { m_i[mi][r] = -__builtin_inff(); l_i[mi][r] = 0.f; }

    const int ktiles = 2*qt + 2;
    stageK(0);
    stageV(0, 0);

    for (int kt = 0; kt < ktiles; ++kt) {
        __syncthreads();
        if (kt + 1 < ktiles) stageV(kt+1, (kt+1)&1);

        f32x4 sc[2][4] = {};
        #pragma unroll
        for (int jk = 0; jk < 4; ++jk)
            #pragma unroll
            for (int ds = 0; ds < 4; ++ds) {
                short8 kf = *(const short8*)&Ks[(jk*16 + l16)*128 + (((ds*4 + quad) ^ l16) * 8)];
                #pragma unroll
                for (int mi = 0; mi < 2; ++mi)
                    sc[mi][jk] = __builtin_amdgcn_mfma_f32_16x16x32_bf16(qf[mi][ds], kf, sc[mi][jk], 0, 0, 0);
            }

        __syncthreads();
        if (kt + 1 < ktiles) stageK(kt+1);

        const int k0 = kt*64;
        #pragma unroll
        for (int mi = 0; mi < 2; ++mi) {
            if (k0 + 63 > qbase + mi*16) {
                #pragma unroll
                for (int jk = 0; jk < 4; ++jk) {
                    int kg = k0 + jk*16 + l16;
                    #pragma unroll
                    for (int r = 0; r < 4; ++r)
                        if (kg > qbase + mi*16 + quad*4 + r) sc[mi][jk][r] = -__builtin_inff();
                }
            }
        }

        float alpha[2][4];
        #pragma unroll
        for (int mi = 0; mi < 2; ++mi)
            #pragma unroll
            for (int r = 0; r < 4; ++r) {
                float mx = fmaxf(fmaxf(sc[mi][0][r], sc[mi][1][r]), fmaxf(sc[mi][2][r], sc[mi][3][r]));
                #pragma unroll
                for (int off = 1; off < 16; off <<= 1)
                    mx = fmaxf(mx, __shfl_xor(mx, off));
                float mn = fmaxf(m_i[mi][r], mx);
                alpha[mi][r] = __expf(m_i[mi][r] - mn);
                m_i[mi][r] = mn;
                float s = 0.f;
                #pragma unroll
                for (int jk = 0; jk < 4; ++jk) {
                    float p = __expf(sc[mi][jk][r] - mn);
                    sc[mi][jk][r] = p;
                    s += p;
                }
                l_i[mi][r] = l_i[mi][r] * alpha[mi][r] + s;
            }

        #pragma unroll
        for (int mi = 0; mi < 2; ++mi)
            #pragma unroll
            for (int jk = 0; jk < 4; ++jk)
                #pragma unroll
                for (int r = 0; r < 4; ++r)
                    Pw[wave][(mi*16 + quad*4 + r)*72 + jk*16 + l16] = (short)bf_rne(sc[mi][jk][r]);

        #pragma unroll
        for (int mi = 0; mi < 2; ++mi)
            #pragma unroll
            for (int dt = 0; dt < 8; ++dt)
                #pragma unroll
                for (int r = 0; r < 4; ++r)
                    o[mi][dt][r] *= alpha[mi][r];

        short8 pa[2][2];
        #pragma unroll
        for (int mi = 0; mi < 2; ++mi)
            #pragma unroll
            for (int kk = 0; kk < 2; ++kk)
                pa[mi][kk] = *(const short8*)&Pw[wave][(mi*16 + l16)*72 + kk*32 + quad*8];

        const short* vb = Vt[kt & 1];
        #pragma unroll
        for (int dt = 0; dt < 8; ++dt)
            #pragma unroll
            for (int kk = 0; kk < 2; ++kk) {
                short8 vf = *(const short8*)&vb[(dt*16 + l16)*64 + (((kk*4 + quad) ^ (l16 & 7)) * 8)];
                #pragma unroll
                for (int mi = 0; mi < 2; ++mi)
                    o[mi][dt] = __builtin_amdgcn_mfma_f32_16x16x32_bf16(pa[mi][kk], vf, o[mi][dt], 0, 0, 0);
            }
    }

    #pragma unroll
    for (int mi = 0; mi < 2; ++mi)
        #pragma unroll
        for (int r = 0; r < 4; ++r) {
            float l = l_i[mi][r];
            #pragma unroll
            for (int off = 1; off < 16; off <<= 1)
                l += __shfl_xor(l, off);
            float inv = 1.0f / l;
            int srow = qbase + mi*16 + quad*4 + r;
            size_t obase = ((size_t)b * Ss + srow) * Ee + h * Dd;
            #pragma unroll
            for (int dt = 0; dt < 8; ++dt)
                O[obase + dt*16 + l16] = (short)bf_rne(o[mi][dt][r] * inv);
        }
}

extern "C" void kernel_launch(void* const* d_in, const int* in_sizes, int n_in,
                              void* d_out, int out_size, void* d_ws, size_t ws_size,
                              hipStream_t stream) {
    const float* x_q  = (const float*)d_in[0];
    const float* x_kv = (const float*)d_in[1];
    const float* cosT = (const float*)d_in[2];
    const float* sinT = (const float*)d_in[3];
    const float* wq = (const float*)d_in[4];
    const float* bq = (const float*)d_in[5];
    const float* wk = (const float*)d_in[6];
    const float* bk = (const float*)d_in[7];
    const float* wv = (const float*)d_in[8];
    const float* bv = (const float*)d_in[9];
    const float* wo = (const float*)d_in[10];
    const float* bo = (const float*)d_in[11];

    size_t off = 0;
    auto alloc = [&](size_t bytes) {
        void* p = (char*)d_ws + off;
        off += (bytes + 255) & ~(size_t)255;
        return p;
    };
    const size_t nX = (size_t)Mrows * Ee;
    const size_t nW = (size_t)Ee * Ee;
    // NOTE: the 6 cast outputs must stay contiguous (cast_all writes them as one run)
    short* xq16  = (short*)alloc(nX * 2);
    short* xkv16 = (short*)alloc(nX * 2);
    short* wq16  = (short*)alloc(nW * 2);
    short* wk16  = (short*)alloc(nW * 2);
    short* wv16  = (short*)alloc(nW * 2);
    short* wo16  = (short*)alloc(nW * 2);
    short* Qr    = (short*)alloc(nX * 2);      // [B,H,S,D]
    short* Kr    = (short*)alloc(nX * 2);      // [B,H,S,D]
    short* VTb   = (short*)alloc(nX * 2);      // [B,H,D,S]
    short* Ob    = (short*)alloc(nX * 2);      // [B,S,E]

    // 1) single fused cast
    cast_all_kernel<<<32768, 256, 0, stream>>>(
        (const float4*)x_q, (const float4*)x_kv, (const float4*)wq,
        (const float4*)wk, (const float4*)wv, (const float4*)wo, (ushort4*)xq16);

    // 2) fused QKV projection (Q,K -> [B,H,S,D]; V -> [B,H,D,S])
    qkv_gemm<<<dim3(Mrows/128, 48), 256, 0, stream>>>(
        xq16, xkv16, wq16, wk16, wv16, bq, bk, bv, Qr, Kr, VTb);

    // 3) RoPE on Q (1/sqrt(D) folded) and K, one dispatch
    rope_kernel<<<dim3((Bb*Hh*Ss*64)/256, 2), 256, 0, stream>>>(Qr, Kr, cosT, sinT);

    // 4) causal flash attention -> Ob [B,S,E] bf16
    attn_kernel<<<dim3(16, Bb*Hh), 256, 0, stream>>>(Qr, Kr, VTb, Ob);

    // 5) output projection -> fp32 d_out
    oproj_gemm<<<dim3(Mrows/128, Ee/128), 256, 0, stream>>>(Ob, wo16, bo, (float*)d_out);
}